// Round 3
// baseline (8995.613 us; speedup 1.0000x reference)
//
#include <hip/hip_runtime.h>
#include <math.h>

// ---------------------------------------------------------------------------
// Sizes (fixed by the problem)
//   input_context  [512][768]   output_context [1024][768]
//   fw_wih [1536][768] fw_whh [1536][512] fw_bih/bhh [1536]
//   bw_wih [1536][768] (whh unused: bwd_hs[-1] = one step from h0=0)
//   dec_wih [3072][768] dec_whh [3072][1024] dec_bih/bhh [3072]
//   W_pred [1024][28996]   out [1024][28996] fp32
// ---------------------------------------------------------------------------

typedef unsigned long long u64;

#define NWG 64
#define NT 512

__device__ __forceinline__ float sigmoidf_(float x) {
  return 1.0f / (1.0f + __expf(-x));  // x=-inf-safe: 1/(1+inf)=0
}
__device__ __forceinline__ float tanhf_(float x) {
  const float xx = fminf(fmaxf(x, -15.0f), 15.0f);
  const float e = __expf(2.0f * xx);
  return (e - 1.0f) / (e + 1.0f);
}

__device__ __forceinline__ float wave_reduce_sum(float v) {
#pragma unroll
  for (int s = 1; s < 64; s <<= 1) v += __shfl_xor(v, s, 64);
  return v;
}

// (tag, h) packed in one 8-byte word: a single relaxed agent-scope atomic
// store publishes value + readiness together; tags are the sole correctness
// authority. Epoch counters below are a contention-reducing HINT only.
__device__ __forceinline__ u64 pack_ht(float h, unsigned tag) {
  union { float f; unsigned u; } c; c.f = h;
  return ((u64)tag << 32) | (u64)c.u;
}
__device__ __forceinline__ float pk_h(u64 v) {
  union { unsigned u; float f; } c; c.u = (unsigned)v; return c.f;
}
__device__ __forceinline__ void astore(u64* p, u64 v) {
  __hip_atomic_store(p, v, __ATOMIC_RELAXED, __HIP_MEMORY_SCOPE_AGENT);
}
__device__ __forceinline__ u64 aload(const u64* p) {
  return __hip_atomic_load((u64*)p, __ATOMIC_RELAXED, __HIP_MEMORY_SCOPE_AGENT);
}
__device__ __forceinline__ unsigned cload(const unsigned* p) {
  return __hip_atomic_load((unsigned*)p, __ATOMIC_RELAXED, __HIP_MEMORY_SCOPE_AGENT);
}
__device__ __forceinline__ void cadd(unsigned* p, unsigned v) {
  __hip_atomic_fetch_add(p, v, __ATOMIC_RELAXED, __HIP_MEMORY_SCOPE_AGENT);
}

// Bounded hint-gate: spin on 8 counter lines (one per wave slot, 128B apart)
// until all reach target, or give up after 64 spins (counters are hint-only,
// the fused-tag loop after this is authoritative -> no hang possible).
__device__ __forceinline__ void hint_gate(const unsigned* cnt, unsigned tgt,
                                          int lane) {
  const unsigned* p = cnt + ((lane & 7) << 5);
  int spins = 0;
  while (spins++ < 64) {
    if (__all(cload(p) >= tgt)) break;
  }
}

// ---------------------------------------------------------------------------
// Persistent recurrence kernel. 64 wgs x 512 threads.
// fw encoder: 512 steps, 1 unit/wave. decoder: 1024 steps, 2 units/wave.
// Recurrent weights in registers. Per step: wave0 waits on the counter hint,
// then does ONE fused (tag,h) read (retry loop = authority), stages h into
// ping-pong LDS; barrier; all waves compute; lane0 publishes (h,tag) with one
// 8B atomic store + one counter add. Depth-2 global ping-pong safe as before.
// ---------------------------------------------------------------------------
__global__ __launch_bounds__(NT) void recur_kernel(
    const float* __restrict__ gxfw,    // [512][1536]
    const float* __restrict__ gxdec,   // [1024][3072]
    const float* __restrict__ gxbw,    // [1536]
    const float* __restrict__ whh_fw,  // [1536][512]
    const float* __restrict__ bhh_fw,  // [1536]
    const float* __restrict__ whh_dec, // [3072][1024]
    const float* __restrict__ bhh_dec, // [3072]
    const float* __restrict__ bhh_bw,  // [1536]
    u64* fwbuf,                        // [2][512]  zeroed: (h=0, tag=0)
    u64* decbuf,                       // [2][1024] zeroed
    unsigned* cnt1,                    // [8*32] fw epoch hints (zeroed)
    unsigned* cnt2,                    // [8*32] dec epoch hints (zeroed)
    float* __restrict__ dec_hs)        // [1024][1024]
{
  __shared__ float Hs[2048];  // ping-pong: fw 2x512 (low half), dec 2x1024
  const int tid = threadIdx.x;
  const int wg = blockIdx.x;
  const int wave = tid >> 6;
  const int lane = tid & 63;

  // backward "encoder" = one GRU cell on input row 511 from h0=0 (gh = bhh).
  // Published with tag 512 into decoder slot 0 (elements 512..1023).
  if (wg == 0) {
    const int j = tid;  // NT == 512 == HIDDEN
    const float r = sigmoidf_(gxbw[j] + bhh_bw[j]);
    const float z = sigmoidf_(gxbw[512 + j] + bhh_bw[512 + j]);
    const float n = tanhf_(gxbw[1024 + j] + r * bhh_bw[1024 + j]);
    astore(&decbuf[512 + j], pack_ht((1.0f - z) * n, 512u));
    if (lane == 0) cadd(cnt2 + (wave << 5), 64u);  // hint: 64 elems published
  }

  // ---------------- forward encoder: 512 steps ----------------
  {
    const int u = (wg << 3) + wave;  // 0..511, one unit per wave
    const float br = bhh_fw[u], bz = bhh_fw[512 + u], bn = bhh_fw[1024 + u];
    float4 wr[3][2];  // 3 gate rows x 8 f32 per lane
#pragma unroll
    for (int g = 0; g < 3; ++g) {
      const float* w = whh_fw + (size_t)(g * 512 + u) * 512;
#pragma unroll
      for (int i = 0; i < 2; ++i)
        wr[g][i] = *(const float4*)&w[(i << 8) + (lane << 2)];
    }
    for (int t = 0; t < 512; ++t) {
      const u64* src = fwbuf + ((t & 1) << 9);
      float* hs = Hs + ((t & 1) << 9);
      if (wave == 0) {
        if (t) hint_gate(cnt1, 64u * (unsigned)t, lane);
        u64 v[8];
        for (;;) {  // authoritative fused (tag,h) read; ~1 iter after gate
          bool ok = true;
#pragma unroll
          for (int j = 0; j < 8; ++j) {
            v[j] = aload(src + (j << 6) + lane);
            ok &= ((unsigned)(v[j] >> 32) >= (unsigned)t);
          }
          if (__all(ok)) break;
        }
#pragma unroll
        for (int j = 0; j < 8; ++j) hs[(j << 6) + lane] = pk_h(v[j]);
      }
      // issue gx loads before the barrier (latency hidden under the wait)
      const float* gx = gxfw + (size_t)t * 1536;
      const float g0 = gx[u], g1 = gx[512 + u], g2 = gx[1024 + u];
      __syncthreads();
      const float4 ha = *(const float4*)&hs[lane << 2];
      const float4 hb = *(const float4*)&hs[256 + (lane << 2)];
      float p0 = wr[0][0].x * ha.x + wr[0][0].y * ha.y + wr[0][0].z * ha.z +
                 wr[0][0].w * ha.w + wr[0][1].x * hb.x + wr[0][1].y * hb.y +
                 wr[0][1].z * hb.z + wr[0][1].w * hb.w;
      float p1 = wr[1][0].x * ha.x + wr[1][0].y * ha.y + wr[1][0].z * ha.z +
                 wr[1][0].w * ha.w + wr[1][1].x * hb.x + wr[1][1].y * hb.y +
                 wr[1][1].z * hb.z + wr[1][1].w * hb.w;
      float p2 = wr[2][0].x * ha.x + wr[2][0].y * ha.y + wr[2][0].z * ha.z +
                 wr[2][0].w * ha.w + wr[2][1].x * hb.x + wr[2][1].y * hb.y +
                 wr[2][1].z * hb.z + wr[2][1].w * hb.w;
      p0 = wave_reduce_sum(p0);
      p1 = wave_reduce_sum(p1);
      p2 = wave_reduce_sum(p2);
      if (lane == 0) {
        const float hold = hs[u];
        const float r = sigmoidf_(g0 + p0 + br);
        const float z = sigmoidf_(g1 + p1 + bz);
        const float n = tanhf_(g2 + r * (p2 + bn));
        const float hnew = (1.0f - z) * n + z * hold;
        if (t < 511) {
          astore(fwbuf + (((t + 1) & 1) << 9) + u,
                 pack_ht(hnew, (unsigned)(t + 1)));
          cadd(cnt1 + (wave << 5), 1u);
        } else {
          astore(decbuf + u, pack_ht(hnew, 512u));  // slot 0, tag 512
          cadd(cnt2 + (wave << 5), 1u);
        }
      }
    }
  }
  __syncthreads();  // LDS region handoff fw -> dec

  // ---------------- decoder: 1024 steps ----------------
  {
    const int u0 = (wg << 4) + (wave << 1);  // 2 units per wave
    float bb0[2], bb1[2], bb2[2];
    float4 wr[2][3][4];  // 2 units x 3 gates x 16 f32 per lane
#pragma unroll
    for (int uu = 0; uu < 2; ++uu) {
      bb0[uu] = bhh_dec[u0 + uu];
      bb1[uu] = bhh_dec[1024 + u0 + uu];
      bb2[uu] = bhh_dec[2048 + u0 + uu];
#pragma unroll
      for (int g = 0; g < 3; ++g) {
        const float* w = whh_dec + (size_t)(g * 1024 + u0 + uu) * 1024;
#pragma unroll
        for (int i = 0; i < 4; ++i)
          wr[uu][g][i] = *(const float4*)&w[(i << 8) + (lane << 2)];
      }
    }
    for (int td = 0; td < 1024; ++td) {
      const int t = 512 + td;  // global tag
      const u64* src = decbuf + ((t & 1) << 10);
      float* hs = Hs + ((t & 1) << 10);
      if (wave == 0) {
        // target: seed (fw-final 64 + bw 64 = 128) + 64 per completed step
        hint_gate(cnt2, 128u + 64u * (unsigned)td, lane);
        u64 v[16];
        for (;;) {
          bool ok = true;
#pragma unroll
          for (int j = 0; j < 16; ++j) {
            v[j] = aload(src + (j << 6) + lane);
            ok &= ((unsigned)(v[j] >> 32) >= (unsigned)t);
          }
          if (__all(ok)) break;
        }
#pragma unroll
        for (int j = 0; j < 16; ++j) hs[(j << 6) + lane] = pk_h(v[j]);
      }
      const float* gx = gxdec + (size_t)td * 3072;
      float ga[2], gb[2], gc[2];
#pragma unroll
      for (int uu = 0; uu < 2; ++uu) {
        ga[uu] = gx[u0 + uu];
        gb[uu] = gx[1024 + u0 + uu];
        gc[uu] = gx[2048 + u0 + uu];
      }
      __syncthreads();
      float4 h4[4];
#pragma unroll
      for (int i = 0; i < 4; ++i)
        h4[i] = *(const float4*)&hs[(i << 8) + (lane << 2)];
      float hn[2];
#pragma unroll
      for (int uu = 0; uu < 2; ++uu) {
        float p0 = 0.f, p1 = 0.f, p2 = 0.f;
#pragma unroll
        for (int i = 0; i < 4; ++i) {
          p0 += wr[uu][0][i].x * h4[i].x + wr[uu][0][i].y * h4[i].y +
                wr[uu][0][i].z * h4[i].z + wr[uu][0][i].w * h4[i].w;
          p1 += wr[uu][1][i].x * h4[i].x + wr[uu][1][i].y * h4[i].y +
                wr[uu][1][i].z * h4[i].z + wr[uu][1][i].w * h4[i].w;
          p2 += wr[uu][2][i].x * h4[i].x + wr[uu][2][i].y * h4[i].y +
                wr[uu][2][i].z * h4[i].z + wr[uu][2][i].w * h4[i].w;
        }
        p0 = wave_reduce_sum(p0);
        p1 = wave_reduce_sum(p1);
        p2 = wave_reduce_sum(p2);
        const int u = u0 + uu;
        const float hold = hs[u];
        const float r = sigmoidf_(ga[uu] + p0 + bb0[uu]);
        const float z = sigmoidf_(gb[uu] + p1 + bb1[uu]);
        const float n = tanhf_(gc[uu] + r * (p2 + bb2[uu]));
        hn[uu] = (1.0f - z) * n + z * hold;
        if (lane == 0) {
          astore(decbuf + (((t + 1) & 1) << 10) + u,
                 pack_ht(hn[uu], (unsigned)(t + 1)));
        }
      }
      if (lane == 0) {
        cadd(cnt2 + (wave << 5), 1u);  // one hint add per wave per step
        dec_hs[(size_t)td * 1024 + u0] = hn[0];      // off critical path
        dec_hs[(size_t)td * 1024 + u0 + 1] = hn[1];
      }
    }
  }
}

// ---------------------------------------------------------------------------
// fp32 GEMM, 128x128 tile, BK=16, 256 threads, 8x8 microtile.
//   BT=1: C[M,N] = Amap[M,K] * B[N,K]^T + bias   (input projections)
//   BT=0: C[M,N] = A[M,K]   * B[K,N]   (+bias)   (vocab projection)
// rowmode: 0 identity, 1 decoder shift (row m -> max(m-1,0)), 2 fixed row.
// ---------------------------------------------------------------------------
#define GBM 128
#define GBN 128
#define GBK 16
#define GLDS 132  // +4 pad

template <int BT>
__global__ __launch_bounds__(256) void gemm128(
    const float* __restrict__ A, const float* __restrict__ B,
    const float* __restrict__ bias, float* __restrict__ C, int M, int N, int K,
    int rowmode, int fixedrow) {
  __shared__ float As[GBK][GLDS];
  __shared__ float Bs[GBK][GLDS];
  const int tid = threadIdx.x;
  const int n0 = blockIdx.x * GBN;
  const int m0 = blockIdx.y * GBM;
  const int tx = tid & 15;
  const int ty = tid >> 4;
  float acc[8][8];
#pragma unroll
  for (int i = 0; i < 8; ++i)
#pragma unroll
    for (int j = 0; j < 8; ++j) acc[i][j] = 0.f;

  const int fl = tid >> 1;
  const int fk = (tid & 1) << 3;
  const int am = m0 + fl;
  int asrow = am;
  if (rowmode == 1) asrow = (am == 0) ? 0 : am - 1;
  else if (rowmode == 2) asrow = fixedrow;
  const bool aok = (am < M);
  const bool nfull = (n0 + GBN <= N);

  for (int k0 = 0; k0 < K; k0 += GBK) {
    {
      float4 v0 = make_float4(0.f, 0.f, 0.f, 0.f), v1 = v0;
      if (aok) {
        const float* p = A + (size_t)asrow * K + k0 + fk;
        v0 = *(const float4*)p;
        v1 = *(const float4*)(p + 4);
      }
      As[fk + 0][fl] = v0.x; As[fk + 1][fl] = v0.y;
      As[fk + 2][fl] = v0.z; As[fk + 3][fl] = v0.w;
      As[fk + 4][fl] = v1.x; As[fk + 5][fl] = v1.y;
      As[fk + 6][fl] = v1.z; As[fk + 7][fl] = v1.w;
    }
    if (BT) {
      const int bn = n0 + fl;
      float4 v0 = make_float4(0.f, 0.f, 0.f, 0.f), v1 = v0;
      if (bn < N) {
        const float* p = B + (size_t)bn * K + k0 + fk;
        v0 = *(const float4*)p;
        v1 = *(const float4*)(p + 4);
      }
      Bs[fk + 0][fl] = v0.x; Bs[fk + 1][fl] = v0.y;
      Bs[fk + 2][fl] = v0.z; Bs[fk + 3][fl] = v0.w;
      Bs[fk + 4][fl] = v1.x; Bs[fk + 5][fl] = v1.y;
      Bs[fk + 6][fl] = v1.z; Bs[fk + 7][fl] = v1.w;
    } else {
      const int kl = tid >> 4;
      const int nq = (tid & 15) << 3;
      const float* p = B + (size_t)(k0 + kl) * N + n0 + nq;
      if (nfull) {
        *(float4*)&Bs[kl][nq] = *(const float4*)p;
        *(float4*)&Bs[kl][nq + 4] = *(const float4*)(p + 4);
      } else {
#pragma unroll
        for (int j = 0; j < 8; ++j)
          Bs[kl][nq + j] = (n0 + nq + j < N) ? p[j] : 0.f;
      }
    }
    __syncthreads();
#pragma unroll
    for (int k = 0; k < GBK; ++k) {
      const float4 a0 = *(const float4*)&As[k][ty << 3];
      const float4 a1 = *(const float4*)&As[k][(ty << 3) + 4];
      const float4 b0 = *(const float4*)&Bs[k][tx << 3];
      const float4 b1 = *(const float4*)&Bs[k][(tx << 3) + 4];
      const float av[8] = {a0.x, a0.y, a0.z, a0.w, a1.x, a1.y, a1.z, a1.w};
      const float bv[8] = {b0.x, b0.y, b0.z, b0.w, b1.x, b1.y, b1.z, b1.w};
#pragma unroll
      for (int i = 0; i < 8; ++i)
#pragma unroll
        for (int j = 0; j < 8; ++j) acc[i][j] += av[i] * bv[j];
    }
    __syncthreads();
  }

  const int mb = m0 + (ty << 3);
  const int nb = n0 + (tx << 3);
#pragma unroll
  for (int i = 0; i < 8; ++i) {
    const int m = mb + i;
    if (m >= M) continue;
    float o[8];
#pragma unroll
    for (int j = 0; j < 8; ++j) o[j] = acc[i][j];
    if (nfull) {
      if (bias) {
#pragma unroll
        for (int j = 0; j < 8; ++j) o[j] += bias[nb + j];
      }
      *(float4*)&C[(size_t)m * N + nb] = make_float4(o[0], o[1], o[2], o[3]);
      *(float4*)&C[(size_t)m * N + nb + 4] = make_float4(o[4], o[5], o[6], o[7]);
    } else {
#pragma unroll
      for (int j = 0; j < 8; ++j) {
        const int n = nb + j;
        if (n < N) C[(size_t)m * N + n] = o[j] + (bias ? bias[n] : 0.f);
      }
    }
  }
}

// ---------------------------------------------------------------------------
// Workspace layout (bytes):
//   [0, 8192)        fwbuf  u64[2][512]   (zeroed each launch)
//   [8192, 24576)    decbuf u64[2][1024]  (zeroed each launch)
//   [24576, 25600)   cnt1 u32[8*32]       (zeroed each launch)
//   [25600, 26624)   cnt2 u32[8*32]       (zeroed each launch)
//   [26624, ...)     gxbw f32[1536], gxfw f32[512*1536],
//                    gxdec f32[1024*3072], dec_hs f32[1024*1024]
// ---------------------------------------------------------------------------
extern "C" void kernel_launch(void* const* d_in, const int* in_sizes, int n_in,
                              void* d_out, int out_size, void* d_ws,
                              size_t ws_size, hipStream_t stream) {
  (void)in_sizes; (void)n_in; (void)out_size; (void)ws_size;
  const float* input_context  = (const float*)d_in[0];
  const float* output_context = (const float*)d_in[1];
  const float* fw_wih = (const float*)d_in[2];
  const float* fw_whh = (const float*)d_in[3];
  const float* fw_bih = (const float*)d_in[4];
  const float* fw_bhh = (const float*)d_in[5];
  const float* bw_wih = (const float*)d_in[6];
  const float* bw_bih = (const float*)d_in[8];
  const float* bw_bhh = (const float*)d_in[9];
  const float* dec_wih = (const float*)d_in[10];
  const float* dec_whh = (const float*)d_in[11];
  const float* dec_bih = (const float*)d_in[12];
  const float* dec_bhh = (const float*)d_in[13];
  const float* W_pred  = (const float*)d_in[14];
  float* out = (float*)d_out;

  u64* fwbuf  = (u64*)d_ws;             // 1024 u64
  u64* decbuf = fwbuf + 1024;           // 2048 u64
  unsigned* cnt1 = (unsigned*)(decbuf + 2048);  // 256 u32
  unsigned* cnt2 = cnt1 + 256;                  // 256 u32
  float* wsf  = (float*)d_ws;
  float* gxbw  = wsf + 6656;            // 1536
  float* gxfw  = wsf + 6656 + 1536;     // 512*1536
  float* gxdec = gxfw + 512 * 1536;     // 1024*3072
  float* dec_hs = gxdec + 1024 * 3072;  // 1024*1024

  // zero (tag,h) buffers (tag0 = ready for t=0, h0=0) + hint counters
  hipMemsetAsync(d_ws, 0, 26624, stream);

  const dim3 blk(256);
  gemm128<1><<<dim3(12, 4), blk, 0, stream>>>(
      input_context, fw_wih, fw_bih, gxfw, 512, 1536, 768, 0, 0);
  gemm128<1><<<dim3(12, 1), blk, 0, stream>>>(
      input_context, bw_wih, bw_bih, gxbw, 1, 1536, 768, 2, 511);
  gemm128<1><<<dim3(24, 8), blk, 0, stream>>>(
      output_context, dec_wih, dec_bih, gxdec, 1024, 3072, 768, 1, 0);

  recur_kernel<<<dim3(NWG), dim3(NT), 0, stream>>>(
      gxfw, gxdec, gxbw, fw_whh, fw_bhh, dec_whh, dec_bhh, bw_bhh,
      fwbuf, decbuf, cnt1, cnt2, dec_hs);

  gemm128<0><<<dim3(227, 8), blk, 0, stream>>>(
      dec_hs, W_pred, nullptr, out, 1024, 28996, 1024, 0, 0);
}

// Round 4
// 6823.151 us; speedup vs baseline: 1.3184x; 1.3184x over previous
//
#include <hip/hip_runtime.h>
#include <math.h>

// ---------------------------------------------------------------------------
// Sizes (fixed by the problem)
//   input_context  [512][768]   output_context [1024][768]
//   fw_wih [1536][768] fw_whh [1536][512] fw_bih/bhh [1536]
//   bw_wih [1536][768] (whh unused: bwd_hs[-1] = one step from h0=0)
//   dec_wih [3072][768] dec_whh [3072][1024] dec_bih/bhh [3072]
//   W_pred [1024][28996]   out [1024][28996] fp32
// ---------------------------------------------------------------------------

typedef unsigned long long u64;
typedef unsigned short ushort_t;
typedef __attribute__((ext_vector_type(8))) short short8;   // 8 bf16 (4 VGPR)
typedef __attribute__((ext_vector_type(4))) float f32x4;

#define NWG 64
#define NT 512
#define NV 28996

__device__ __forceinline__ float sigmoidf_(float x) {
  return 1.0f / (1.0f + __expf(-x));
}
__device__ __forceinline__ float tanhf_(float x) {
  const float xx = fminf(fmaxf(x, -15.0f), 15.0f);
  const float e = __expf(2.0f * xx);
  return (e - 1.0f) / (e + 1.0f);
}
__device__ __forceinline__ ushort_t f2bf(float f) {
  union { float f; unsigned u; } c; c.f = f;
  unsigned u = c.u;
  u += 0x7fffu + ((u >> 16) & 1u);  // RNE
  return (ushort_t)(u >> 16);
}

__device__ __forceinline__ float wave_reduce_sum(float v) {
#pragma unroll
  for (int s = 1; s < 64; s <<= 1) v += __shfl_xor(v, s, 64);
  return v;
}

// keep a float4 pinned in VGPRs (blocks rematerialization-from-memory)
__device__ __forceinline__ void pin4(float4& v) {
  asm volatile("" : "+v"(v.x), "+v"(v.y), "+v"(v.z), "+v"(v.w));
}

// (tag, h) fused in one 8-byte word: single relaxed agent-scope atomic store
// publishes value + readiness together. Tags are the sole sync authority.
__device__ __forceinline__ u64 pack_ht(float h, unsigned tag) {
  union { float f; unsigned u; } c; c.f = h;
  return ((u64)tag << 32) | (u64)c.u;
}
__device__ __forceinline__ float pk_h(u64 v) {
  union { unsigned u; float f; } c; c.u = (unsigned)v; return c.f;
}
__device__ __forceinline__ void astore(u64* p, u64 v) {
  __hip_atomic_store(p, v, __ATOMIC_RELAXED, __HIP_MEMORY_SCOPE_AGENT);
}
__device__ __forceinline__ u64 aload(const u64* p) {
  return __hip_atomic_load((u64*)p, __ATOMIC_RELAXED, __HIP_MEMORY_SCOPE_AGENT);
}

// ---------------------------------------------------------------------------
// Persistent recurrence kernel. 64 wgs x 512 threads.
// Masked incremental poll: each lane re-reads ONLY the slots whose tag is
// still stale, so steady-state poll traffic is just the laggard lines.
// During step-t reads a slot holds tag t-2 or t (depth-2 proof: t+2 is
// written only after all wgs published t+1, which requires their step-t
// reads to have completed) -> ">= t" check, successful reads are final.
// ---------------------------------------------------------------------------
__global__ __launch_bounds__(NT, 2) void recur_kernel(
    const float* __restrict__ gxfw,    // [512][1536]
    const float* __restrict__ gxdec,   // [1024][3072]
    const float* __restrict__ gxbw,    // [1536]
    const float* __restrict__ whh_fw,  // [1536][512]
    const float* __restrict__ bhh_fw,  // [1536]
    const float* __restrict__ whh_dec, // [3072][1024]
    const float* __restrict__ bhh_dec, // [3072]
    const float* __restrict__ bhh_bw,  // [1536]
    u64* fwbuf,                        // [2][512]  zeroed: (h=0, tag=0)
    u64* decbuf,                       // [2][1024] zeroed
    float* __restrict__ dec_hs,        // [1024][1024] f32 (fallback GEMM)
    ushort_t* __restrict__ dec_hs_bf,  // [1024][1024] bf16 (MFMA GEMM)
    int do_bf16)
{
  __shared__ float Hs[2048];  // ping-pong: fw 2x512 (low half), dec 2x1024
  const int tid = threadIdx.x;
  const int wg = blockIdx.x;
  const int wave = tid >> 6;
  const int lane = tid & 63;

  // backward "encoder" = one GRU cell on input row 511 from h0=0 (gh = bhh).
  if (wg == 0) {
    const int j = tid;  // NT == 512 == HIDDEN
    const float r = sigmoidf_(gxbw[j] + bhh_bw[j]);
    const float z = sigmoidf_(gxbw[512 + j] + bhh_bw[512 + j]);
    const float n = tanhf_(gxbw[1024 + j] + r * bhh_bw[1024 + j]);
    astore(&decbuf[512 + j], pack_ht((1.0f - z) * n, 512u));
  }

  // ---------------- forward encoder: 512 steps ----------------
  {
    const int u = (wg << 3) + wave;  // 0..511, one unit per wave
    const float br = bhh_fw[u], bz = bhh_fw[512 + u], bn = bhh_fw[1024 + u];
    float4 wr[3][2];  // 3 gate rows x 8 f32 per lane, pinned in VGPRs
#pragma unroll
    for (int g = 0; g < 3; ++g) {
      const float* w = whh_fw + (size_t)(g * 512 + u) * 512;
#pragma unroll
      for (int i = 0; i < 2; ++i) {
        wr[g][i] = *(const float4*)&w[(i << 8) + (lane << 2)];
        pin4(wr[g][i]);
      }
    }
    for (int t = 0; t < 512; ++t) {
      const u64* src = fwbuf + ((t & 1) << 9);
      float* hs = Hs + ((t & 1) << 9);
      // gx loads issued before poll/barrier (latency hidden under the wait)
      const float* gx = gxfw + (size_t)t * 1536;
      const float g0 = gx[u], g1 = gx[512 + u], g2 = gx[1024 + u];
      if (wave == 0) {  // masked incremental poll + LDS stage
        u64 v[8];
        unsigned need = 0xFFu;
        for (;;) {
          unsigned nnew = 0;
#pragma unroll
          for (int j = 0; j < 8; ++j) {
            if ((need >> j) & 1u) {
              v[j] = aload(src + (j << 6) + lane);
              if ((unsigned)(v[j] >> 32) < (unsigned)t) nnew |= 1u << j;
            }
          }
          need = nnew;
          if (__all(need == 0)) break;
        }
#pragma unroll
        for (int j = 0; j < 8; ++j) hs[(j << 6) + lane] = pk_h(v[j]);
      }
      __syncthreads();
      const float4 ha = *(const float4*)&hs[lane << 2];
      const float4 hb = *(const float4*)&hs[256 + (lane << 2)];
      float p0 = wr[0][0].x * ha.x + wr[0][0].y * ha.y + wr[0][0].z * ha.z +
                 wr[0][0].w * ha.w + wr[0][1].x * hb.x + wr[0][1].y * hb.y +
                 wr[0][1].z * hb.z + wr[0][1].w * hb.w;
      float p1 = wr[1][0].x * ha.x + wr[1][0].y * ha.y + wr[1][0].z * ha.z +
                 wr[1][0].w * ha.w + wr[1][1].x * hb.x + wr[1][1].y * hb.y +
                 wr[1][1].z * hb.z + wr[1][1].w * hb.w;
      float p2 = wr[2][0].x * ha.x + wr[2][0].y * ha.y + wr[2][0].z * ha.z +
                 wr[2][0].w * ha.w + wr[2][1].x * hb.x + wr[2][1].y * hb.y +
                 wr[2][1].z * hb.z + wr[2][1].w * hb.w;
      p0 = wave_reduce_sum(p0);
      p1 = wave_reduce_sum(p1);
      p2 = wave_reduce_sum(p2);
      if (lane == 0) {
        const float hold = hs[u];
        const float r = sigmoidf_(g0 + p0 + br);
        const float z = sigmoidf_(g1 + p1 + bz);
        const float n = tanhf_(g2 + r * (p2 + bn));
        const float hnew = (1.0f - z) * n + z * hold;
        if (t < 511)
          astore(fwbuf + (((t + 1) & 1) << 9) + u,
                 pack_ht(hnew, (unsigned)(t + 1)));
        else
          astore(decbuf + u, pack_ht(hnew, 512u));  // slot 0, tag 512
      }
    }
  }
  __syncthreads();  // LDS region handoff fw -> dec

  // ---------------- decoder: 1024 steps ----------------
  {
    const int u0 = (wg << 4) + (wave << 1);  // 2 units per wave
    float bb0[2], bb1[2], bb2[2];
    float4 wr[2][3][4];  // 2 units x 3 gates x 16 f32 per lane, pinned
#pragma unroll
    for (int uu = 0; uu < 2; ++uu) {
      bb0[uu] = bhh_dec[u0 + uu];
      bb1[uu] = bhh_dec[1024 + u0 + uu];
      bb2[uu] = bhh_dec[2048 + u0 + uu];
#pragma unroll
      for (int g = 0; g < 3; ++g) {
        const float* w = whh_dec + (size_t)(g * 1024 + u0 + uu) * 1024;
#pragma unroll
        for (int i = 0; i < 4; ++i) {
          wr[uu][g][i] = *(const float4*)&w[(i << 8) + (lane << 2)];
          pin4(wr[uu][g][i]);
        }
      }
    }
    for (int td = 0; td < 1024; ++td) {
      const int t = 512 + td;  // global tag
      const u64* src = decbuf + ((t & 1) << 10);
      float* hs = Hs + ((t & 1) << 10);
      const float* gx = gxdec + (size_t)td * 3072;
      float ga[2], gb[2], gc[2];
#pragma unroll
      for (int uu = 0; uu < 2; ++uu) {
        ga[uu] = gx[u0 + uu];
        gb[uu] = gx[1024 + u0 + uu];
        gc[uu] = gx[2048 + u0 + uu];
      }
      if (wave < 2) {  // two polling waves, 8 slots (512 u64) each
        const u64* s2 = src + (wave << 9);
        float* h2 = hs + (wave << 9);
        u64 v[8];
        unsigned need = 0xFFu;
        for (;;) {
          unsigned nnew = 0;
#pragma unroll
          for (int j = 0; j < 8; ++j) {
            if ((need >> j) & 1u) {
              v[j] = aload(s2 + (j << 6) + lane);
              if ((unsigned)(v[j] >> 32) < (unsigned)t) nnew |= 1u << j;
            }
          }
          need = nnew;
          if (__all(need == 0)) break;
        }
#pragma unroll
        for (int j = 0; j < 8; ++j) h2[(j << 6) + lane] = pk_h(v[j]);
      }
      __syncthreads();
      float4 h4[4];
#pragma unroll
      for (int i = 0; i < 4; ++i)
        h4[i] = *(const float4*)&hs[(i << 8) + (lane << 2)];
      float hn[2];
#pragma unroll
      for (int uu = 0; uu < 2; ++uu) {
        float p0 = 0.f, p1 = 0.f, p2 = 0.f;
#pragma unroll
        for (int i = 0; i < 4; ++i) {
          p0 += wr[uu][0][i].x * h4[i].x + wr[uu][0][i].y * h4[i].y +
                wr[uu][0][i].z * h4[i].z + wr[uu][0][i].w * h4[i].w;
          p1 += wr[uu][1][i].x * h4[i].x + wr[uu][1][i].y * h4[i].y +
                wr[uu][1][i].z * h4[i].z + wr[uu][1][i].w * h4[i].w;
          p2 += wr[uu][2][i].x * h4[i].x + wr[uu][2][i].y * h4[i].y +
                wr[uu][2][i].z * h4[i].z + wr[uu][2][i].w * h4[i].w;
        }
        p0 = wave_reduce_sum(p0);
        p1 = wave_reduce_sum(p1);
        p2 = wave_reduce_sum(p2);
        const int u = u0 + uu;
        const float hold = hs[u];
        const float r = sigmoidf_(ga[uu] + p0 + bb0[uu]);
        const float z = sigmoidf_(gb[uu] + p1 + bb1[uu]);
        const float n = tanhf_(gc[uu] + r * (p2 + bb2[uu]));
        hn[uu] = (1.0f - z) * n + z * hold;
        if (lane == 0) {
          astore(decbuf + (((t + 1) & 1) << 10) + u,
                 pack_ht(hn[uu], (unsigned)(t + 1)));
        }
      }
      if (lane == 0) {  // off critical path
        dec_hs[(size_t)td * 1024 + u0] = hn[0];
        dec_hs[(size_t)td * 1024 + u0 + 1] = hn[1];
        if (do_bf16) {
          dec_hs_bf[(size_t)td * 1024 + u0] = f2bf(hn[0]);
          dec_hs_bf[(size_t)td * 1024 + u0 + 1] = f2bf(hn[1]);
        }
      }
    }
  }
}

// ---------------------------------------------------------------------------
// W_pred [1024][28996] f32  ->  Wt [28996][1024] bf16 (k-contiguous rows).
// 64x64 LDS-tiled transpose, coalesced on both sides.
// ---------------------------------------------------------------------------
__global__ __launch_bounds__(256) void wt_transpose(
    const float* __restrict__ W, ushort_t* __restrict__ Wt) {
  __shared__ float T[64][65];
  const int tid = threadIdx.x;
  const int n0 = blockIdx.x * 64;
  const int k0 = blockIdx.y * 64;
  const int nloc = tid & 63;
  const int q = tid >> 6;  // 0..3
  const bool nok = (n0 + nloc) < NV;
#pragma unroll
  for (int r = 0; r < 16; ++r) {
    const int kloc = q + r * 4;
    T[kloc][nloc] = nok ? W[(size_t)(k0 + kloc) * NV + n0 + nloc] : 0.f;
  }
  __syncthreads();
  const int kloc2 = tid & 63;
#pragma unroll
  for (int w = 0; w < 16; ++w) {
    const int nloc2 = q + w * 4;
    if (n0 + nloc2 < NV)
      Wt[(size_t)(n0 + nloc2) * 1024 + k0 + kloc2] = f2bf(T[kloc2][nloc2]);
  }
}

// ---------------------------------------------------------------------------
// bf16 MFMA vocab GEMM: out[1024][28996] = dec_hs_bf[1024][1024] x W_pred,
// with B pre-transposed as Wt[28996][1024] bf16 (k-contiguous rows).
// 128x128 tile, BK=64, 512 threads = 8 waves (4M x 2N), 16x16x32 MFMA.
// Frag layouts (gfx950, §3): A lane l: row=l&15, k=(l>>4)*8+j;
// B lane l: col=l&15, k=(l>>4)*8+j; D lane l: col=l&15, row=(l>>4)*4+reg.
// Both LDS tiles stored row-major-in-k with +8 pad (72): all ds reads/writes
// bank-uniform.
// ---------------------------------------------------------------------------
__global__ __launch_bounds__(512) void gemm_vocab_bf16(
    const ushort_t* __restrict__ A,   // [1024][1024] bf16
    const ushort_t* __restrict__ Bt,  // [28996][1024] bf16
    float* __restrict__ C) {          // [1024][28996] f32
  __shared__ short As[128 * 72];
  __shared__ short Bs[128 * 72];
  const int tid = threadIdx.x;
  const int lane = tid & 63;
  const int wid = tid >> 6;
  const int wm = wid >> 1;   // 0..3
  const int wn = wid & 1;    // 0..1
  const int n0 = blockIdx.x * 128;
  const int m0 = blockIdx.y * 128;

  const int frow = tid >> 2;          // 0..127 (fill row)
  const int fko = (tid & 3) << 4;     // k offset 0/16/32/48
  const bool bok = (n0 + frow) < NV;
  const uint4 zz = make_uint4(0, 0, 0, 0);

  f32x4 acc[2][4];
#pragma unroll
  for (int i = 0; i < 2; ++i)
#pragma unroll
    for (int j = 0; j < 4; ++j) acc[i][j] = (f32x4){0.f, 0.f, 0.f, 0.f};

  for (int k0 = 0; k0 < 1024; k0 += 64) {
    {  // A fill: 128 rows x 64 k bf16, 32B per thread
      const uint4* s = (const uint4*)(A + (size_t)(m0 + frow) * 1024 + k0 + fko);
      uint4* d = (uint4*)&As[frow * 72 + fko];
      d[0] = s[0];
      d[1] = s[1];
    }
    {  // B fill from Wt rows (n-major, k-contiguous)
      uint4 v0 = zz, v1 = zz;
      if (bok) {
        const uint4* s =
            (const uint4*)(Bt + (size_t)(n0 + frow) * 1024 + k0 + fko);
        v0 = s[0];
        v1 = s[1];
      }
      uint4* d = (uint4*)&Bs[frow * 72 + fko];
      d[0] = v0;
      d[1] = v1;
    }
    __syncthreads();
#pragma unroll
    for (int ks = 0; ks < 64; ks += 32) {
      short8 a[2], b[4];
#pragma unroll
      for (int fm = 0; fm < 2; ++fm)
        a[fm] = *(const short8*)&As[(wm * 32 + fm * 16 + (lane & 15)) * 72 +
                                    ks + ((lane >> 4) << 3)];
#pragma unroll
      for (int fn = 0; fn < 4; ++fn)
        b[fn] = *(const short8*)&Bs[(wn * 64 + fn * 16 + (lane & 15)) * 72 +
                                    ks + ((lane >> 4) << 3)];
#pragma unroll
      for (int fm = 0; fm < 2; ++fm)
#pragma unroll
        for (int fn = 0; fn < 4; ++fn)
          acc[fm][fn] = __builtin_amdgcn_mfma_f32_16x16x32_bf16(
              a[fm], b[fn], acc[fm][fn], 0, 0, 0);
    }
    __syncthreads();
  }

#pragma unroll
  for (int fm = 0; fm < 2; ++fm) {
#pragma unroll
    for (int fn = 0; fn < 4; ++fn) {
      const int col = n0 + wn * 64 + fn * 16 + (lane & 15);
      if (col < NV) {
        const int rbase = m0 + wm * 32 + fm * 16 + ((lane >> 4) << 2);
#pragma unroll
        for (int r = 0; r < 4; ++r)
          C[(size_t)(rbase + r) * NV + col] = acc[fm][fn][r];
      }
    }
  }
}

// ---------------------------------------------------------------------------
// fp32 GEMM, 128x128 tile, BK=16, 256 threads, 8x8 microtile.
//   BT=1: C[M,N] = Amap[M,K] * B[N,K]^T + bias   (input projections)
//   BT=0: C[M,N] = A[M,K]   * B[K,N]   (+bias)   (vocab fallback)
// rowmode: 0 identity, 1 decoder shift (row m -> max(m-1,0)), 2 fixed row.
// ---------------------------------------------------------------------------
#define GBM 128
#define GBN 128
#define GBK 16
#define GLDS 132

template <int BT>
__global__ __launch_bounds__(256) void gemm128(
    const float* __restrict__ A, const float* __restrict__ B,
    const float* __restrict__ bias, float* __restrict__ C, int M, int N, int K,
    int rowmode, int fixedrow) {
  __shared__ float As[GBK][GLDS];
  __shared__ float Bs[GBK][GLDS];
  const int tid = threadIdx.x;
  const int n0 = blockIdx.x * GBN;
  const int m0 = blockIdx.y * GBM;
  const int tx = tid & 15;
  const int ty = tid >> 4;
  float acc[8][8];
#pragma unroll
  for (int i = 0; i < 8; ++i)
#pragma unroll
    for (int j = 0; j < 8; ++j) acc[i][j] = 0.f;

  const int fl = tid >> 1;
  const int fk = (tid & 1) << 3;
  const int am = m0 + fl;
  int asrow = am;
  if (rowmode == 1) asrow = (am == 0) ? 0 : am - 1;
  else if (rowmode == 2) asrow = fixedrow;
  const bool aok = (am < M);
  const bool nfull = (n0 + GBN <= N);

  for (int k0 = 0; k0 < K; k0 += GBK) {
    {
      float4 v0 = make_float4(0.f, 0.f, 0.f, 0.f), v1 = v0;
      if (aok) {
        const float* p = A + (size_t)asrow * K + k0 + fk;
        v0 = *(const float4*)p;
        v1 = *(const float4*)(p + 4);
      }
      As[fk + 0][fl] = v0.x; As[fk + 1][fl] = v0.y;
      As[fk + 2][fl] = v0.z; As[fk + 3][fl] = v0.w;
      As[fk + 4][fl] = v1.x; As[fk + 5][fl] = v1.y;
      As[fk + 6][fl] = v1.z; As[fk + 7][fl] = v1.w;
    }
    if (BT) {
      const int bn = n0 + fl;
      float4 v0 = make_float4(0.f, 0.f, 0.f, 0.f), v1 = v0;
      if (bn < N) {
        const float* p = B + (size_t)bn * K + k0 + fk;
        v0 = *(const float4*)p;
        v1 = *(const float4*)(p + 4);
      }
      Bs[fk + 0][fl] = v0.x; Bs[fk + 1][fl] = v0.y;
      Bs[fk + 2][fl] = v0.z; Bs[fk + 3][fl] = v0.w;
      Bs[fk + 4][fl] = v1.x; Bs[fk + 5][fl] = v1.y;
      Bs[fk + 6][fl] = v1.z; Bs[fk + 7][fl] = v1.w;
    } else {
      const int kl = tid >> 4;
      const int nq = (tid & 15) << 3;
      const float* p = B + (size_t)(k0 + kl) * N + n0 + nq;
      if (nfull) {
        *(float4*)&Bs[kl][nq] = *(const float4*)p;
        *(float4*)&Bs[kl][nq + 4] = *(const float4*)(p + 4);
      } else {
#pragma unroll
        for (int j = 0; j < 8; ++j)
          Bs[kl][nq + j] = (n0 + nq + j < N) ? p[j] : 0.f;
      }
    }
    __syncthreads();
#pragma unroll
    for (int k = 0; k < GBK; ++k) {
      const float4 a0 = *(const float4*)&As[k][ty << 3];
      const float4 a1 = *(const float4*)&As[k][(ty << 3) + 4];
      const float4 b0 = *(const float4*)&Bs[k][tx << 3];
      const float4 b1 = *(const float4*)&Bs[k][(tx << 3) + 4];
      const float av[8] = {a0.x, a0.y, a0.z, a0.w, a1.x, a1.y, a1.z, a1.w};
      const float bv[8] = {b0.x, b0.y, b0.z, b0.w, b1.x, b1.y, b1.z, b1.w};
#pragma unroll
      for (int i = 0; i < 8; ++i)
#pragma unroll
        for (int j = 0; j < 8; ++j) acc[i][j] += av[i] * bv[j];
    }
    __syncthreads();
  }

  const int mb = m0 + (ty << 3);
  const int nb = n0 + (tx << 3);
#pragma unroll
  for (int i = 0; i < 8; ++i) {
    const int m = mb + i;
    if (m >= M) continue;
    float o[8];
#pragma unroll
    for (int j = 0; j < 8; ++j) o[j] = acc[i][j];
    if (nfull) {
      if (bias) {
#pragma unroll
        for (int j = 0; j < 8; ++j) o[j] += bias[nb + j];
      }
      *(float4*)&C[(size_t)m * N + nb] = make_float4(o[0], o[1], o[2], o[3]);
      *(float4*)&C[(size_t)m * N + nb + 4] = make_float4(o[4], o[5], o[6], o[7]);
    } else {
#pragma unroll
      for (int j = 0; j < 8; ++j) {
        const int n = nb + j;
        if (n < N) C[(size_t)m * N + n] = o[j] + (bias ? bias[n] : 0.f);
      }
    }
  }
}

// ---------------------------------------------------------------------------
// Workspace layout (byte offsets):
//   0         fwbuf  u64[1024]        (zeroed each launch)
//   8192      decbuf u64[2048]        (zeroed each launch)
//   24576     gxbw   f32[1536]
//   30720     gxfw   f32[512*1536]
//   3176448   gxdec  f32[1024*3072]
//   15759360  dec_hs f32[1024*1024]
//   19953664  dec_hs_bf16 u16[1024*1024]
//   22050816  Wt bf16 u16[28996*1024]   -> end 81434624 (~81.5 MB)
// bf16 path requires ws_size >= 81434624; else fp32 fallback (<20 MB).
// ---------------------------------------------------------------------------
extern "C" void kernel_launch(void* const* d_in, const int* in_sizes, int n_in,
                              void* d_out, int out_size, void* d_ws,
                              size_t ws_size, hipStream_t stream) {
  (void)in_sizes; (void)n_in; (void)out_size;
  const float* input_context  = (const float*)d_in[0];
  const float* output_context = (const float*)d_in[1];
  const float* fw_wih = (const float*)d_in[2];
  const float* fw_whh = (const float*)d_in[3];
  const float* fw_bih = (const float*)d_in[4];
  const float* fw_bhh = (const float*)d_in[5];
  const float* bw_wih = (const float*)d_in[6];
  const float* bw_bih = (const float*)d_in[8];
  const float* bw_bhh = (const float*)d_in[9];
  const float* dec_wih = (const float*)d_in[10];
  const float* dec_whh = (const float*)d_in[11];
  const float* dec_bih = (const float*)d_in[12];
  const float* dec_bhh = (const float*)d_in[13];
  const float* W_pred  = (const float*)d_in[14];
  float* out = (float*)d_out;

  char* wsb = (char*)d_ws;
  u64* fwbuf   = (u64*)wsb;
  u64* decbuf  = (u64*)(wsb + 8192);
  float* gxbw  = (float*)(wsb + 24576);
  float* gxfw  = (float*)(wsb + 30720);
  float* gxdec = (float*)(wsb + 3176448);
  float* dec_hs = (float*)(wsb + 15759360);
  ushort_t* dec_hs_bf = (ushort_t*)(wsb + 19953664);
  ushort_t* Wt = (ushort_t*)(wsb + 22050816);
  const int do_bf16 = (ws_size >= 81434624u) ? 1 : 0;

  // zero the (tag,h) buffers: tag=0 (= ready only for t=0), h0=0
  hipMemsetAsync(d_ws, 0, 24576, stream);

  const dim3 blk(256);
  gemm128<1><<<dim3(12, 4), blk, 0, stream>>>(
      input_context, fw_wih, fw_bih, gxfw, 512, 1536, 768, 0, 0);
  gemm128<1><<<dim3(12, 1), blk, 0, stream>>>(
      input_context, bw_wih, bw_bih, gxbw, 1, 1536, 768, 2, 511);
  gemm128<1><<<dim3(24, 8), blk, 0, stream>>>(
      output_context, dec_wih, dec_bih, gxdec, 1024, 3072, 768, 1, 0);
  if (do_bf16)
    wt_transpose<<<dim3(454, 16), blk, 0, stream>>>(W_pred, Wt);

  recur_kernel<<<dim3(NWG), dim3(NT), 0, stream>>>(
      gxfw, gxdec, gxbw, fw_whh, fw_bhh, dec_whh, dec_bhh, bw_bhh,
      fwbuf, decbuf, dec_hs, dec_hs_bf, do_bf16);

  if (do_bf16)
    gemm_vocab_bf16<<<dim3(227, 8), dim3(512), 0, stream>>>(
        dec_hs_bf, Wt, out);
  else
    gemm128<0><<<dim3(227, 8), blk, 0, stream>>>(
        dec_hs, W_pred, nullptr, out, 1024, NV, 1024, 0, 0);
}

// Round 5
// 6631.381 us; speedup vs baseline: 1.3565x; 1.0289x over previous
//
#include <hip/hip_runtime.h>
#include <math.h>

// ---------------------------------------------------------------------------
// Sizes (fixed by the problem)
//   input_context  [512][768]   output_context [1024][768]
//   fw_wih [1536][768] fw_whh [1536][512] fw_bih/bhh [1536]
//   bw_wih [1536][768] (whh unused: bwd_hs[-1] = one step from h0=0)
//   dec_wih [3072][768] dec_whh [3072][1024] dec_bih/bhh [3072]
//   W_pred [1024][28996]   out [1024][28996] fp32
// ---------------------------------------------------------------------------

typedef unsigned long long u64;
typedef unsigned short ushort_t;
typedef __attribute__((ext_vector_type(8))) short short8;   // 8 bf16 (4 VGPR)
typedef __attribute__((ext_vector_type(4))) float f32x4;

#define NWG 64
#define NT 512
#define NV 28996

__device__ __forceinline__ float sigmoidf_(float x) {
  return 1.0f / (1.0f + __expf(-x));
}
__device__ __forceinline__ float tanhf_(float x) {
  const float xx = fminf(fmaxf(x, -15.0f), 15.0f);
  const float e = __expf(2.0f * xx);
  return (e - 1.0f) / (e + 1.0f);
}
__device__ __forceinline__ ushort_t f2bf(float f) {
  union { float f; unsigned u; } c; c.f = f;
  unsigned u = c.u;
  u += 0x7fffu + ((u >> 16) & 1u);  // RNE
  return (ushort_t)(u >> 16);
}

__device__ __forceinline__ float wave_reduce_sum(float v) {
#pragma unroll
  for (int s = 1; s < 64; s <<= 1) v += __shfl_xor(v, s, 64);
  return v;
}

// In-loop VGPR pin: "+v" def each iteration forbids rematerialization from
// memory -> the weight vector MUST stay register-resident across the loop.
__device__ __forceinline__ void pinv(f32x4& v) {
  asm volatile("" : "+v"(v));
}

// (tag, h) fused in one 8-byte word: single relaxed agent-scope atomic store
// publishes value + readiness together. Tags are the sole sync authority.
__device__ __forceinline__ u64 pack_ht(float h, unsigned tag) {
  union { float f; unsigned u; } c; c.f = h;
  return ((u64)tag << 32) | (u64)c.u;
}
__device__ __forceinline__ float pk_h(u64 v) {
  union { unsigned u; float f; } c; c.u = (unsigned)v; return c.f;
}
__device__ __forceinline__ void astore(u64* p, u64 v) {
  __hip_atomic_store(p, v, __ATOMIC_RELAXED, __HIP_MEMORY_SCOPE_AGENT);
}
__device__ __forceinline__ u64 aload(const u64* p) {
  return __hip_atomic_load((u64*)p, __ATOMIC_RELAXED, __HIP_MEMORY_SCOPE_AGENT);
}

// ---------------------------------------------------------------------------
// Persistent recurrence kernel. 64 wgs x 512 threads.
// Per step: poll (masked incremental) -> LDS stage -> B1 -> compute (weights
// pinned in VGPRs) -> hnew to LDS hstage -> B2 -> ONE coalesced exec-masked
// atomic-store instruction publishes the wg's whole 64B/128B output line
// (one fabric transaction; all tags in the line flip together).
// Depth-2 ping-pong safety unchanged: tag t+2 overwrites a slot only after
// all wgs published t+1, which requires their step-t reads completed.
// ---------------------------------------------------------------------------
__global__ __launch_bounds__(NT, 2) void recur_kernel(
    const float* __restrict__ gxfw,    // [512][1536]
    const float* __restrict__ gxdec,   // [1024][3072]
    const float* __restrict__ gxbw,    // [1536]
    const float* __restrict__ whh_fw,  // [1536][512]
    const float* __restrict__ bhh_fw,  // [1536]
    const float* __restrict__ whh_dec, // [3072][1024]
    const float* __restrict__ bhh_dec, // [3072]
    const float* __restrict__ bhh_bw,  // [1536]
    u64* fwbuf,                        // [2][512]  zeroed: (h=0, tag=0)
    u64* decbuf,                       // [2][1024] zeroed
    float* __restrict__ dec_hs,        // [1024][1024] f32 (fallback GEMM)
    ushort_t* __restrict__ dec_hs_bf,  // [1024][1024] bf16 (MFMA GEMM)
    int do_bf16)
{
  __shared__ float Hs[2048];     // ping-pong: fw 2x512 (low half), dec 2x1024
  __shared__ float hstage[16];   // per-step publish staging
  const int tid = threadIdx.x;
  const int wg = blockIdx.x;
  const int wave = tid >> 6;
  const int lane = tid & 63;

  // backward "encoder" = one GRU cell on input row 511 from h0=0 (gh = bhh).
  if (wg == 0) {
    const int j = tid;  // NT == 512 == HIDDEN
    const float r = sigmoidf_(gxbw[j] + bhh_bw[j]);
    const float z = sigmoidf_(gxbw[512 + j] + bhh_bw[512 + j]);
    const float n = tanhf_(gxbw[1024 + j] + r * bhh_bw[1024 + j]);
    astore(&decbuf[512 + j], pack_ht((1.0f - z) * n, 512u));
  }

  // ---------------- forward encoder: 512 steps ----------------
  {
    const int u = (wg << 3) + wave;  // 0..511, one unit per wave
    const float br = bhh_fw[u], bz = bhh_fw[512 + u], bn = bhh_fw[1024 + u];
    f32x4 wr[3][2];  // 3 gate rows x 8 f32 per lane
#pragma unroll
    for (int g = 0; g < 3; ++g) {
      const float* w = whh_fw + (size_t)(g * 512 + u) * 512;
#pragma unroll
      for (int i = 0; i < 2; ++i)
        wr[g][i] = *(const f32x4*)&w[(i << 8) + (lane << 2)];
    }
    for (int t = 0; t < 512; ++t) {
      const u64* src = fwbuf + ((t & 1) << 9);
      float* hs = Hs + ((t & 1) << 9);
      // gx loads issued before poll/barrier (latency hidden under the wait)
      const float* gx = gxfw + (size_t)t * 1536;
      const float g0 = gx[u], g1 = gx[512 + u], g2 = gx[1024 + u];
      if (wave == 0) {  // masked incremental poll + LDS stage
        u64 v[8];
        unsigned need = 0xFFu;
        for (;;) {
          unsigned nnew = 0;
#pragma unroll
          for (int j = 0; j < 8; ++j) {
            if ((need >> j) & 1u) {
              v[j] = aload(src + (j << 6) + lane);
              if ((unsigned)(v[j] >> 32) < (unsigned)t) nnew |= 1u << j;
            }
          }
          need = nnew;
          if (__all(need == 0)) break;
        }
#pragma unroll
        for (int j = 0; j < 8; ++j) hs[(j << 6) + lane] = pk_h(v[j]);
      }
      __syncthreads();  // B1
#pragma unroll
      for (int g = 0; g < 3; ++g)
#pragma unroll
        for (int i = 0; i < 2; ++i) pinv(wr[g][i]);
      const f32x4 ha = *(const f32x4*)&hs[lane << 2];
      const f32x4 hb = *(const f32x4*)&hs[256 + (lane << 2)];
      float p0 = wr[0][0][0] * ha[0] + wr[0][0][1] * ha[1] +
                 wr[0][0][2] * ha[2] + wr[0][0][3] * ha[3] +
                 wr[0][1][0] * hb[0] + wr[0][1][1] * hb[1] +
                 wr[0][1][2] * hb[2] + wr[0][1][3] * hb[3];
      float p1 = wr[1][0][0] * ha[0] + wr[1][0][1] * ha[1] +
                 wr[1][0][2] * ha[2] + wr[1][0][3] * ha[3] +
                 wr[1][1][0] * hb[0] + wr[1][1][1] * hb[1] +
                 wr[1][1][2] * hb[2] + wr[1][1][3] * hb[3];
      float p2 = wr[2][0][0] * ha[0] + wr[2][0][1] * ha[1] +
                 wr[2][0][2] * ha[2] + wr[2][0][3] * ha[3] +
                 wr[2][1][0] * hb[0] + wr[2][1][1] * hb[1] +
                 wr[2][1][2] * hb[2] + wr[2][1][3] * hb[3];
      p0 = wave_reduce_sum(p0);
      p1 = wave_reduce_sum(p1);
      p2 = wave_reduce_sum(p2);
      if (lane == 0) {
        const float hold = hs[u];
        const float r = sigmoidf_(g0 + p0 + br);
        const float z = sigmoidf_(g1 + p1 + bz);
        const float n = tanhf_(g2 + r * (p2 + bn));
        hstage[wave] = (1.0f - z) * n + z * hold;
      }
      __syncthreads();  // B2
      if (tid < 8) {  // ONE coalesced 64B publish (8 lanes x u64, one instr)
        u64* dst = ((t < 511) ? (fwbuf + (((t + 1) & 1) << 9)) : decbuf) +
                   (wg << 3) + tid;
        astore(dst, pack_ht(hstage[tid], (unsigned)(t + 1)));
      }
    }
  }
  __syncthreads();  // LDS region handoff fw -> dec

  // ---------------- decoder: 1024 steps ----------------
  {
    const int u0 = (wg << 4) + (wave << 1);  // 2 units per wave
    float bb0[2], bb1[2], bb2[2];
    f32x4 wr[2][3][4];  // 2 units x 3 gates x 16 f32 per lane, pinned
#pragma unroll
    for (int uu = 0; uu < 2; ++uu) {
      bb0[uu] = bhh_dec[u0 + uu];
      bb1[uu] = bhh_dec[1024 + u0 + uu];
      bb2[uu] = bhh_dec[2048 + u0 + uu];
#pragma unroll
      for (int g = 0; g < 3; ++g) {
        const float* w = whh_dec + (size_t)(g * 1024 + u0 + uu) * 1024;
#pragma unroll
        for (int i = 0; i < 4; ++i)
          wr[uu][g][i] = *(const f32x4*)&w[(i << 8) + (lane << 2)];
      }
    }
    for (int td = 0; td < 1024; ++td) {
      const int t = 512 + td;  // global tag
      const u64* src = decbuf + ((t & 1) << 10);
      float* hs = Hs + ((t & 1) << 10);
      const float* gx = gxdec + (size_t)td * 3072;
      float ga[2], gb[2], gc[2];
#pragma unroll
      for (int uu = 0; uu < 2; ++uu) {
        ga[uu] = gx[u0 + uu];
        gb[uu] = gx[1024 + u0 + uu];
        gc[uu] = gx[2048 + u0 + uu];
      }
      if (wave < 2) {  // two polling waves, 8 slot-groups (512 u64) each
        const u64* s2 = src + (wave << 9);
        float* h2 = hs + (wave << 9);
        u64 v[8];
        unsigned need = 0xFFu;
        for (;;) {
          unsigned nnew = 0;
#pragma unroll
          for (int j = 0; j < 8; ++j) {
            if ((need >> j) & 1u) {
              v[j] = aload(s2 + (j << 6) + lane);
              if ((unsigned)(v[j] >> 32) < (unsigned)t) nnew |= 1u << j;
            }
          }
          need = nnew;
          if (__all(need == 0)) break;
        }
#pragma unroll
        for (int j = 0; j < 8; ++j) h2[(j << 6) + lane] = pk_h(v[j]);
      }
      __syncthreads();  // B1
#pragma unroll
      for (int uu = 0; uu < 2; ++uu)
#pragma unroll
        for (int g = 0; g < 3; ++g)
#pragma unroll
          for (int i = 0; i < 4; ++i) pinv(wr[uu][g][i]);
      f32x4 h4[4];
#pragma unroll
      for (int i = 0; i < 4; ++i)
        h4[i] = *(const f32x4*)&hs[(i << 8) + (lane << 2)];
      float hn[2];
#pragma unroll
      for (int uu = 0; uu < 2; ++uu) {
        float p0 = 0.f, p1 = 0.f, p2 = 0.f;
#pragma unroll
        for (int i = 0; i < 4; ++i) {
          p0 += wr[uu][0][i][0] * h4[i][0] + wr[uu][0][i][1] * h4[i][1] +
                wr[uu][0][i][2] * h4[i][2] + wr[uu][0][i][3] * h4[i][3];
          p1 += wr[uu][1][i][0] * h4[i][0] + wr[uu][1][i][1] * h4[i][1] +
                wr[uu][1][i][2] * h4[i][2] + wr[uu][1][i][3] * h4[i][3];
          p2 += wr[uu][2][i][0] * h4[i][0] + wr[uu][2][i][1] * h4[i][1] +
                wr[uu][2][i][2] * h4[i][2] + wr[uu][2][i][3] * h4[i][3];
        }
        p0 = wave_reduce_sum(p0);
        p1 = wave_reduce_sum(p1);
        p2 = wave_reduce_sum(p2);
        const int u = u0 + uu;
        const float hold = hs[u];
        const float r = sigmoidf_(ga[uu] + p0 + bb0[uu]);
        const float z = sigmoidf_(gb[uu] + p1 + bb1[uu]);
        const float n = tanhf_(gc[uu] + r * (p2 + bb2[uu]));
        hn[uu] = (1.0f - z) * n + z * hold;
      }
      if (lane == 0) {
        hstage[(wave << 1)] = hn[0];
        hstage[(wave << 1) + 1] = hn[1];
      }
      __syncthreads();  // B2
      if (tid < 16) {  // ONE coalesced 128B publish (16 lanes x u64)
        const float h = hstage[tid];
        astore(decbuf + (((t + 1) & 1) << 10) + (wg << 4) + tid,
               pack_ht(h, (unsigned)(t + 1)));
        if (do_bf16)
          dec_hs_bf[(size_t)td * 1024 + (wg << 4) + tid] = f2bf(h);
        else
          dec_hs[(size_t)td * 1024 + (wg << 4) + tid] = h;
      }
    }
  }
}

// ---------------------------------------------------------------------------
// W_pred [1024][28996] f32  ->  Wt [28996][1024] bf16 (k-contiguous rows).
// 64x64 LDS-tiled transpose, coalesced on both sides.
// ---------------------------------------------------------------------------
__global__ __launch_bounds__(256) void wt_transpose(
    const float* __restrict__ W, ushort_t* __restrict__ Wt) {
  __shared__ float T[64][65];
  const int tid = threadIdx.x;
  const int n0 = blockIdx.x * 64;
  const int k0 = blockIdx.y * 64;
  const int nloc = tid & 63;
  const int q = tid >> 6;  // 0..3
  const bool nok = (n0 + nloc) < NV;
#pragma unroll
  for (int r = 0; r < 16; ++r) {
    const int kloc = q + r * 4;
    T[kloc][nloc] = nok ? W[(size_t)(k0 + kloc) * NV + n0 + nloc] : 0.f;
  }
  __syncthreads();
  const int kloc2 = tid & 63;
#pragma unroll
  for (int w = 0; w < 16; ++w) {
    const int nloc2 = q + w * 4;
    if (n0 + nloc2 < NV)
      Wt[(size_t)(n0 + nloc2) * 1024 + k0 + kloc2] = f2bf(T[kloc2][nloc2]);
  }
}

// ---------------------------------------------------------------------------
// bf16 MFMA vocab GEMM: out[1024][28996] = dec_hs_bf[1024][1024] x W_pred,
// with B pre-transposed as Wt[28996][1024] bf16 (k-contiguous rows).
// 128x128 tile, BK=64, 512 threads = 8 waves (4M x 2N), 16x16x32 MFMA.
// ---------------------------------------------------------------------------
__global__ __launch_bounds__(512) void gemm_vocab_bf16(
    const ushort_t* __restrict__ A,   // [1024][1024] bf16
    const ushort_t* __restrict__ Bt,  // [28996][1024] bf16
    float* __restrict__ C) {          // [1024][28996] f32
  __shared__ short As[128 * 72];
  __shared__ short Bs[128 * 72];
  const int tid = threadIdx.x;
  const int lane = tid & 63;
  const int wid = tid >> 6;
  const int wm = wid >> 1;   // 0..3
  const int wn = wid & 1;    // 0..1
  const int n0 = blockIdx.x * 128;
  const int m0 = blockIdx.y * 128;

  const int frow = tid >> 2;          // 0..127 (fill row)
  const int fko = (tid & 3) << 4;     // k offset 0/16/32/48
  const bool bok = (n0 + frow) < NV;
  const uint4 zz = make_uint4(0, 0, 0, 0);

  f32x4 acc[2][4];
#pragma unroll
  for (int i = 0; i < 2; ++i)
#pragma unroll
    for (int j = 0; j < 4; ++j) acc[i][j] = (f32x4){0.f, 0.f, 0.f, 0.f};

  for (int k0 = 0; k0 < 1024; k0 += 64) {
    {  // A fill: 128 rows x 64 k bf16, 32B per thread
      const uint4* s = (const uint4*)(A + (size_t)(m0 + frow) * 1024 + k0 + fko);
      uint4* d = (uint4*)&As[frow * 72 + fko];
      d[0] = s[0];
      d[1] = s[1];
    }
    {  // B fill from Wt rows (n-major, k-contiguous)
      uint4 v0 = zz, v1 = zz;
      if (bok) {
        const uint4* s =
            (const uint4*)(Bt + (size_t)(n0 + frow) * 1024 + k0 + fko);
        v0 = s[0];
        v1 = s[1];
      }
      uint4* d = (uint4*)&Bs[frow * 72 + fko];
      d[0] = v0;
      d[1] = v1;
    }
    __syncthreads();
#pragma unroll
    for (int ks = 0; ks < 64; ks += 32) {
      short8 a[2], b[4];
#pragma unroll
      for (int fm = 0; fm < 2; ++fm)
        a[fm] = *(const short8*)&As[(wm * 32 + fm * 16 + (lane & 15)) * 72 +
                                    ks + ((lane >> 4) << 3)];
#pragma unroll
      for (int fn = 0; fn < 4; ++fn)
        b[fn] = *(const short8*)&Bs[(wn * 64 + fn * 16 + (lane & 15)) * 72 +
                                    ks + ((lane >> 4) << 3)];
#pragma unroll
      for (int fm = 0; fm < 2; ++fm)
#pragma unroll
        for (int fn = 0; fn < 4; ++fn)
          acc[fm][fn] = __builtin_amdgcn_mfma_f32_16x16x32_bf16(
              a[fm], b[fn], acc[fm][fn], 0, 0, 0);
    }
    __syncthreads();
  }

#pragma unroll
  for (int fm = 0; fm < 2; ++fm) {
#pragma unroll
    for (int fn = 0; fn < 4; ++fn) {
      const int col = n0 + wn * 64 + fn * 16 + (lane & 15);
      if (col < NV) {
        const int rbase = m0 + wm * 32 + fm * 16 + ((lane >> 4) << 2);
#pragma unroll
        for (int r = 0; r < 4; ++r)
          C[(size_t)(rbase + r) * NV + col] = acc[fm][fn][r];
      }
    }
  }
}

// ---------------------------------------------------------------------------
// fp32 GEMM, 128x128 tile, BK=16, 256 threads, 8x8 microtile.
//   BT=1: C[M,N] = Amap[M,K] * B[N,K]^T + bias   (input projections)
//   BT=0: C[M,N] = A[M,K]   * B[K,N]   (+bias)   (vocab fallback)
// rowmode: 0 identity, 1 decoder shift (row m -> max(m-1,0)), 2 fixed row.
// ---------------------------------------------------------------------------
#define GBM 128
#define GBN 128
#define GBK 16
#define GLDS 132

template <int BT>
__global__ __launch_bounds__(256) void gemm128(
    const float* __restrict__ A, const float* __restrict__ B,
    const float* __restrict__ bias, float* __restrict__ C, int M, int N, int K,
    int rowmode, int fixedrow) {
  __shared__ float As[GBK][GLDS];
  __shared__ float Bs[GBK][GLDS];
  const int tid = threadIdx.x;
  const int n0 = blockIdx.x * GBN;
  const int m0 = blockIdx.y * GBM;
  const int tx = tid & 15;
  const int ty = tid >> 4;
  float acc[8][8];
#pragma unroll
  for (int i = 0; i < 8; ++i)
#pragma unroll
    for (int j = 0; j < 8; ++j) acc[i][j] = 0.f;

  const int fl = tid >> 1;
  const int fk = (tid & 1) << 3;
  const int am = m0 + fl;
  int asrow = am;
  if (rowmode == 1) asrow = (am == 0) ? 0 : am - 1;
  else if (rowmode == 2) asrow = fixedrow;
  const bool aok = (am < M);
  const bool nfull = (n0 + GBN <= N);

  for (int k0 = 0; k0 < K; k0 += GBK) {
    {
      float4 v0 = make_float4(0.f, 0.f, 0.f, 0.f), v1 = v0;
      if (aok) {
        const float* p = A + (size_t)asrow * K + k0 + fk;
        v0 = *(const float4*)p;
        v1 = *(const float4*)(p + 4);
      }
      As[fk + 0][fl] = v0.x; As[fk + 1][fl] = v0.y;
      As[fk + 2][fl] = v0.z; As[fk + 3][fl] = v0.w;
      As[fk + 4][fl] = v1.x; As[fk + 5][fl] = v1.y;
      As[fk + 6][fl] = v1.z; As[fk + 7][fl] = v1.w;
    }
    if (BT) {
      const int bn = n0 + fl;
      float4 v0 = make_float4(0.f, 0.f, 0.f, 0.f), v1 = v0;
      if (bn < N) {
        const float* p = B + (size_t)bn * K + k0 + fk;
        v0 = *(const float4*)p;
        v1 = *(const float4*)(p + 4);
      }
      Bs[fk + 0][fl] = v0.x; Bs[fk + 1][fl] = v0.y;
      Bs[fk + 2][fl] = v0.z; Bs[fk + 3][fl] = v0.w;
      Bs[fk + 4][fl] = v1.x; Bs[fk + 5][fl] = v1.y;
      Bs[fk + 6][fl] = v1.z; Bs[fk + 7][fl] = v1.w;
    } else {
      const int kl = tid >> 4;
      const int nq = (tid & 15) << 3;
      const float* p = B + (size_t)(k0 + kl) * N + n0 + nq;
      if (nfull) {
        *(float4*)&Bs[kl][nq] = *(const float4*)p;
        *(float4*)&Bs[kl][nq + 4] = *(const float4*)(p + 4);
      } else {
#pragma unroll
        for (int j = 0; j < 8; ++j)
          Bs[kl][nq + j] = (n0 + nq + j < N) ? p[j] : 0.f;
      }
    }
    __syncthreads();
#pragma unroll
    for (int k = 0; k < GBK; ++k) {
      const float4 a0 = *(const float4*)&As[k][ty << 3];
      const float4 a1 = *(const float4*)&As[k][(ty << 3) + 4];
      const float4 b0 = *(const float4*)&Bs[k][tx << 3];
      const float4 b1 = *(const float4*)&Bs[k][(tx << 3) + 4];
      const float av[8] = {a0.x, a0.y, a0.z, a0.w, a1.x, a1.y, a1.z, a1.w};
      const float bv[8] = {b0.x, b0.y, b0.z, b0.w, b1.x, b1.y, b1.z, b1.w};
#pragma unroll
      for (int i = 0; i < 8; ++i)
#pragma unroll
        for (int j = 0; j < 8; ++j) acc[i][j] += av[i] * bv[j];
    }
    __syncthreads();
  }

  const int mb = m0 + (ty << 3);
  const int nb = n0 + (tx << 3);
#pragma unroll
  for (int i = 0; i < 8; ++i) {
    const int m = mb + i;
    if (m >= M) continue;
    float o[8];
#pragma unroll
    for (int j = 0; j < 8; ++j) o[j] = acc[i][j];
    if (nfull) {
      if (bias) {
#pragma unroll
        for (int j = 0; j < 8; ++j) o[j] += bias[nb + j];
      }
      *(float4*)&C[(size_t)m * N + nb] = make_float4(o[0], o[1], o[2], o[3]);
      *(float4*)&C[(size_t)m * N + nb + 4] = make_float4(o[4], o[5], o[6], o[7]);
    } else {
#pragma unroll
      for (int j = 0; j < 8; ++j) {
        const int n = nb + j;
        if (n < N) C[(size_t)m * N + n] = o[j] + (bias ? bias[n] : 0.f);
      }
    }
  }
}

// ---------------------------------------------------------------------------
// Workspace layout (byte offsets):
//   0         fwbuf  u64[1024]        (zeroed each launch)
//   8192      decbuf u64[2048]        (zeroed each launch)
//   24576     gxbw   f32[1536]
//   30720     gxfw   f32[512*1536]
//   3176448   gxdec  f32[1024*3072]
//   15759360  dec_hs f32[1024*1024]
//   19953664  dec_hs_bf16 u16[1024*1024]
//   22050816  Wt bf16 u16[28996*1024]   -> end 81434624 (~81.5 MB)
// bf16 path requires ws_size >= 81434624; else fp32 fallback (<20 MB).
// ---------------------------------------------------------------------------
extern "C" void kernel_launch(void* const* d_in, const int* in_sizes, int n_in,
                              void* d_out, int out_size, void* d_ws,
                              size_t ws_size, hipStream_t stream) {
  (void)in_sizes; (void)n_in; (void)out_size;
  const float* input_context  = (const float*)d_in[0];
  const float* output_context = (const float*)d_in[1];
  const float* fw_wih = (const float*)d_in[2];
  const float* fw_whh = (const float*)d_in[3];
  const float* fw_bih = (const float*)d_in[4];
  const float* fw_bhh = (const float*)d_in[5];
  const float* bw_wih = (const float*)d_in[6];
  const float* bw_bih = (const float*)d_in[8];
  const float* bw_bhh = (const float*)d_in[9];
  const float* dec_wih = (const float*)d_in[10];
  const float* dec_whh = (const float*)d_in[11];
  const float* dec_bih = (const float*)d_in[12];
  const float* dec_bhh = (const float*)d_in[13];
  const float* W_pred  = (const float*)d_in[14];
  float* out = (float*)d_out;

  char* wsb = (char*)d_ws;
  u64* fwbuf   = (u64*)wsb;
  u64* decbuf  = (u64*)(wsb + 8192);
  float* gxbw  = (float*)(wsb + 24576);
  float* gxfw  = (float*)(wsb + 30720);
  float* gxdec = (float*)(wsb + 3176448);
  float* dec_hs = (float*)(wsb + 15759360);
  ushort_t* dec_hs_bf = (ushort_t*)(wsb + 19953664);
  ushort_t* Wt = (ushort_t*)(wsb + 22050816);
  const int do_bf16 = (ws_size >= 81434624u) ? 1 : 0;

  // zero the (tag,h) buffers: tag=0 (= ready only for t=0), h0=0
  hipMemsetAsync(d_ws, 0, 24576, stream);

  const dim3 blk(256);
  gemm128<1><<<dim3(12, 4), blk, 0, stream>>>(
      input_context, fw_wih, fw_bih, gxfw, 512, 1536, 768, 0, 0);
  gemm128<1><<<dim3(12, 1), blk, 0, stream>>>(
      input_context, bw_wih, bw_bih, gxbw, 1, 1536, 768, 2, 511);
  gemm128<1><<<dim3(24, 8), blk, 0, stream>>>(
      output_context, dec_wih, dec_bih, gxdec, 1024, 3072, 768, 1, 0);
  if (do_bf16)
    wt_transpose<<<dim3(454, 16), blk, 0, stream>>>(W_pred, Wt);

  recur_kernel<<<dim3(NWG), dim3(NT), 0, stream>>>(
      gxfw, gxdec, gxbw, fw_whh, fw_bhh, dec_whh, dec_bhh, bw_bhh,
      fwbuf, decbuf, dec_hs, dec_hs_bf, do_bf16);

  if (do_bf16)
    gemm_vocab_bf16<<<dim3(227, 8), dim3(512), 0, stream>>>(
        dec_hs_bf, Wt, out);
  else
    gemm128<0><<<dim3(227, 8), blk, 0, stream>>>(
        dec_hs, W_pred, nullptr, out, 1024, NV, 1024, 0, 0);
}